// Round 7
// baseline (2933.003 us; speedup 1.0000x reference)
//
#include <hip/hip_runtime.h>
#include <hip/hip_bf16.h>

typedef __attribute__((ext_vector_type(4))) float f32x4;
typedef __attribute__((ext_vector_type(8))) short short8;
typedef __attribute__((ext_vector_type(8))) unsigned short ushort8;

#define T_STEPS 512
#define BATCH   128
#define IDIM    512
#define HDIM    1024
#define KTOT    1536           // IDIM + HDIM (fused [x_t | h] @ [Wx; Wh])
#define NGROUP  8              // batch groups (16 rows each)
#define GROWS   16             // batch rows per group
#define NCB     16             // column-blocks per group
#define CBW     64             // output columns per block (4 waves x 16)
#define HBUF_ELEMS (BATCH * HDIM)    // per SLOT (3 slots)
#define XBUFB   (GROWS * IDIM * 2)   // bytes per xs half
#define HSBUFB  (GROWS * HDIM * 2)   // bytes per hs half (32 KB)
#define NFLAG   (NGROUP * 64)        // per-WAVE global flags, packed 4B

// f32 -> bf16 round-to-nearest-even
__device__ __forceinline__ unsigned short f2bf(float f) {
    unsigned int u = __builtin_bit_cast(unsigned int, f);
    u = (u + 0x7FFFu + ((u >> 16) & 1u)) >> 16;
    return (unsigned short)u;
}

// fast tanh: clamp +-9, e2x = exp2(2*log2e*x), (e2x-1)*rcp(e2x+1).
__device__ __forceinline__ float fast_tanh(float x) {
    x = fminf(9.0f, fmaxf(-9.0f, x));
    float t = __builtin_exp2f(x * 2.8853900817779268f);
    return (t - 1.0f) * __builtin_amdgcn_rcpf(t + 1.0f);
}

// XOR swizzles (row strides 0 mod 128B; XOR row low-bits into the 16B-slot index)
__device__ __forceinline__ int swzX(int row, int c) { return row * 1024 + (c ^ ((row & 7) << 4)); }
__device__ __forceinline__ int swzH(int row, int c) { return row * 2048 + (c ^ ((row & 7) << 4)); }

// ---- proven IF-coherent primitives (sc0 sc1) -------------------------------
// Session ledger: sc0-only = CU scope (deadlock, R1); sc1-only = no win (R2);
// 2x poll traffic = +13% (R2); s_sleep pacing regressions (R3); data-as-flag
// heavy poll = livelock (R5); C^T packed epilogue = +12% (R6: kills
// quarter-wave store coalescing). R0 datapath+protocol restored verbatim.
__device__ __forceinline__ void st_h16_if(unsigned short* p, unsigned short v) {
    asm volatile("global_store_short %0, %1, off sc0 sc1" :: "v"(p), "v"(v) : "memory");
}
__device__ __forceinline__ void st_u32_if(unsigned int* p, unsigned int v) {
    asm volatile("global_store_dword %0, %1, off sc0 sc1" :: "v"(p), "v"(v) : "memory");
}
__device__ __forceinline__ unsigned int ld_u32_if(const unsigned int* p) {
    unsigned int v;
    asm volatile("global_load_dword %0, %1, off sc0 sc1\n\ts_waitcnt vmcnt(0)"
                 : "=v"(v) : "v"(p) : "memory");
    return v;
}
// issue 8 pipelined dwordx4 h-tile loads (128 B), NO wait (drained by counted vmcnt)
__device__ __forceinline__ void ldh_issue_if(const unsigned short* p, ushort8 v[8]) {
    asm volatile(
        "global_load_dwordx4 %0, %8, off sc0 sc1\n\t"
        "global_load_dwordx4 %1, %8, off offset:16 sc0 sc1\n\t"
        "global_load_dwordx4 %2, %8, off offset:32 sc0 sc1\n\t"
        "global_load_dwordx4 %3, %8, off offset:48 sc0 sc1\n\t"
        "global_load_dwordx4 %4, %8, off offset:64 sc0 sc1\n\t"
        "global_load_dwordx4 %5, %8, off offset:80 sc0 sc1\n\t"
        "global_load_dwordx4 %6, %8, off offset:96 sc0 sc1\n\t"
        "global_load_dwordx4 %7, %8, off offset:112 sc0 sc1"
        : "=&v"(v[0]), "=&v"(v[1]), "=&v"(v[2]), "=&v"(v[3]),
          "=&v"(v[4]), "=&v"(v[5]), "=&v"(v[6]), "=&v"(v[7])
        : "v"(p) : "memory");
}
// issue 8 pipelined dwordx4 x-tile loads (128 B of f32), normal caching, NO wait
__device__ __forceinline__ void ldx_issue(const float* p, float4 v[8]) {
    asm volatile(
        "global_load_dwordx4 %0, %8, off\n\t"
        "global_load_dwordx4 %1, %8, off offset:16\n\t"
        "global_load_dwordx4 %2, %8, off offset:32\n\t"
        "global_load_dwordx4 %3, %8, off offset:48\n\t"
        "global_load_dwordx4 %4, %8, off offset:64\n\t"
        "global_load_dwordx4 %5, %8, off offset:80\n\t"
        "global_load_dwordx4 %6, %8, off offset:96\n\t"
        "global_load_dwordx4 %7, %8, off offset:112"
        : "=&v"(v[0]), "=&v"(v[1]), "=&v"(v[2]), "=&v"(v[3]),
          "=&v"(v[4]), "=&v"(v[5]), "=&v"(v[6]), "=&v"(v[7])
        : "v"(p) : "memory");
}

// ---- elastic per-wave LDS sync ---------------------------------------------
// Spin until all 4 waves' flags >= tgt. Volatile LDS reads (~60cy, wave-local
// SIMD, zero L2 traffic — evades the R2/R5 poll-traffic trap).
__device__ __forceinline__ void spin_ge(volatile int* f, int tgt) {
    while (f[0] < tgt || f[1] < tgt || f[2] < tgt || f[3] < tgt) { }
    __builtin_amdgcn_sched_barrier(0);
}
// Publish: order after prior LDS data writes, then lane-0 volatile store.
__device__ __forceinline__ void flag_set(volatile int* p, int v, int lane) {
    asm volatile("s_waitcnt lgkmcnt(0)" ::: "memory");
    __builtin_amdgcn_sched_barrier(0);
    if (lane == 0) *p = v;
    asm volatile("s_waitcnt lgkmcnt(0)" ::: "memory");
}

// ---------------------------------------------------------------------------
// Prep: WT[n][k] = bf16(W[k][n]) for W in {Wx (koff=0), Wh (koff=IDIM)}.
__global__ void prep_transpose(const float* __restrict__ src,
                               unsigned short* __restrict__ dst, int koff) {
    __shared__ float tl[32][33];
    const int tx = threadIdx.x, ty = threadIdx.y;
    const int k0 = blockIdx.x * 32, n0 = blockIdx.y * 32;
#pragma unroll
    for (int q = 0; q < 4; ++q) {
        int kk = ty * 4 + q;
        tl[kk][tx] = src[(size_t)(k0 + kk) * HDIM + n0 + tx];
    }
    __syncthreads();
#pragma unroll
    for (int q = 0; q < 4; ++q) {
        int nn = ty * 4 + q;
        dst[(size_t)(n0 + nn) * KTOT + koff + k0 + tx] = f2bf(tl[tx][nn]);
    }
}

// Prep: hbuf slot0=bf16(h0); bsum=bx+bh; flags=0. (Slots 1,2 of hbuf are
// never read before being written: flag protocol guards them.)
__global__ void prep_misc(const float* __restrict__ h0, const float* __restrict__ bx,
                          const float* __restrict__ bh, float* __restrict__ bsum,
                          unsigned short* __restrict__ hbuf, unsigned int* __restrict__ flags) {
    int idx = blockIdx.x * 256 + threadIdx.x;
    if (idx < HBUF_ELEMS) {
        hbuf[idx] = f2bf(h0[idx]);
    } else if (idx < HBUF_ELEMS + HDIM) {
        int j = idx - HBUF_ELEMS;
        bsum[j] = bx[j] + bh[j];
    } else if (idx < HBUF_ELEMS + HDIM + NFLAG) {
        flags[idx - HBUF_ELEMS - HDIM] = 0;
    }
}

__global__ void ws_fail_kernel(float* out) { out[0] = 1.0e6f; }  // ws_size diagnostic

// ---------------------------------------------------------------------------
// Fused recurrence, ELASTIC WAVES. R0 datapath/protocol verbatim; the two
// per-step block barriers are replaced by per-wave LDS sequence flags so each
// wave carries ~1 step of slack instead of rendezvousing (lockstep convoy =
// max-of-4 jitter per step, the theory for the unexplained ~half of the 10k-cy
// step). hs is DOUBLE-buffered in LDS (96 KB total; gfx950 allows >64KB/WG),
// global hbuf is TRIPLE-buffered (skew<=2 across the diameter-2 flag graph:
// writer of h(t+1) has 2-hop evidence all waves published flag t-1, which
// postdates their h(t-2) read retirement => slot (t+1)%3 is reusable).
// Flags: stage_x[w] = x(t) staged | stage_h[w] = h(t) staged | done[w] = D(t)
// reads finished. Conditions: B(t): stage_x>=t; C-write(t): done>=t-2;
// D(t): stage_h>=t; G-write(t): done>=t-1 (checked at C, which precedes G).
__global__ __launch_bounds__(256, 1) void rnn_fused(
        const float* __restrict__ x, const unsigned short* __restrict__ WT,
        const float* __restrict__ bsum, unsigned short* __restrict__ hbuf,
        unsigned int* __restrict__ flags, float* __restrict__ out) {
    __shared__ unsigned short xs[2 * GROWS * IDIM];   // 32 KB (double-buffered x tile)
    __shared__ unsigned short hs[2 * GROWS * HDIM];   // 64 KB (double-buffered h tile)
    __shared__ int wf[12];   // [0..3] stage_x, [4..7] stage_h, [8..11] done
    char* xb = (char*)xs;
    char* hb = (char*)hs;
    volatile int* const f_sx = wf;
    volatile int* const f_sh = wf + 4;
    volatile int* const f_dn = wf + 8;
    const int tid  = threadIdx.x;
    const int bid  = blockIdx.x;
    const int g    = bid & 7;
    const int cb   = bid >> 3;
    const int lane = tid & 63;
    const int wid  = tid >> 6;
    const int lrow = lane & 15;    // A row / C col low bits
    const int kg   = lane >> 4;    // k-group 0..3
    const int ncol = cb * CBW + wid * 16 + lrow;

    // Resident B fragments: lane holds WT[ncol][kc*32 + kg*8 .. +7]
    short8 Bf[48];
    {
        const short8* wp = (const short8*)(WT + (size_t)ncol * KTOT);
#pragma unroll
        for (int kc = 0; kc < 48; ++kc) Bf[kc] = wp[kc * 4 + kg];
    }
#pragma unroll
    for (int kc = 0; kc < 48; ++kc) asm volatile("" : "+v"(Bf[kc]));
    const float bias = bsum[ncol];

    const int sm  = tid & 15;      // staged row 0..15
    const int seg = tid >> 4;      // 1/16 of the row
    unsigned int* const myflag = &flags[(g << 6) + (cb << 2) + wid];
    // wave w's staged columns come from producer blocks 4w..4w+3 only:
    // lane checks flag of producer block (wid*4 + lane>>4), wave sub-flag lane&3
    const unsigned int* const pollp =
        &flags[(g << 6) + (((wid << 2) + (lane >> 4)) << 2) + (lane & 3)];
    const size_t rowoff = (size_t)(g * GROWS + sm) * HDIM + seg * 64;

    // ---- prologue: stage x(0) into xs buf 0; init this wave's flags ----
    {
        float4 xv0[8];
        ldx_issue(x + ((size_t)g * GROWS + sm) * IDIM + seg * 32, xv0);
        asm volatile("s_waitcnt vmcnt(0)" ::: "memory");
        __builtin_amdgcn_sched_barrier(0);
#pragma unroll
        for (int q = 0; q < 4; ++q) {
            float4 a = xv0[2 * q], b = xv0[2 * q + 1];
            ushort8 w;
            w[0] = f2bf(a.x); w[1] = f2bf(a.y); w[2] = f2bf(a.z); w[3] = f2bf(a.w);
            w[4] = f2bf(b.x); w[5] = f2bf(b.y); w[6] = f2bf(b.z); w[7] = f2bf(b.w);
            *(ushort8*)(xb + swzX(sm, seg * 64 + q * 16)) = w;
        }
        if (lane == 0) { f_sx[wid] = 0; f_sh[wid] = -1; f_dn[wid] = -1; }
        asm volatile("s_waitcnt lgkmcnt(0)" ::: "memory");
        __builtin_amdgcn_s_barrier();          // ONLY barrier in the kernel
        __builtin_amdgcn_sched_barrier(0);
    }

    int sl = 0;                                // h read slot = t % 3
    for (int t = 0; t < T_STEPS; ++t) {
        const bool has_next = (t + 1 < T_STEPS);
        const int slw = (sl == 2) ? 0 : sl + 1;   // h write slot = (t+1) % 3

        // ---- A0: per-wave quartet poll (flags carry value t after F(t-1)) ----
        {
            const unsigned int tgt = (unsigned int)t;
            while (true) {
                unsigned int v = ld_u32_if(pollp);
                if (__all(v >= tgt)) break;    // no s_sleep: vmcnt RT paces the loop
            }
        }

        // ---- A: issue h(t) loads FIRST (oldest in queue), then x(t+1) ----
        ushort8 hv[8];
        ldh_issue_if(hbuf + (size_t)sl * HBUF_ELEMS + rowoff, hv);
        float4 xv[8];
        if (has_next)
            ldx_issue(x + ((size_t)(t + 1) * BATCH + g * GROWS + sm) * IDIM + seg * 32, xv);

        // ---- B: x-MFMA under load latency (xs[t&1] staged by all at G(t-1)) ----
        spin_ge(f_sx, t);
        const char* xcur = xb + (t & 1) * XBUFB;
        f32x4 acc0 = {0.f, 0.f, 0.f, 0.f}, acc1 = acc0, acc2 = acc0, acc3 = acc0;
#pragma unroll
        for (int kk = 0; kk < 4; ++kk) {
            short8 a0 = *(const short8*)(xcur + swzX(lrow, (4 * kk + 0) * 64 + kg * 16));
            short8 a1 = *(const short8*)(xcur + swzX(lrow, (4 * kk + 1) * 64 + kg * 16));
            short8 a2 = *(const short8*)(xcur + swzX(lrow, (4 * kk + 2) * 64 + kg * 16));
            short8 a3 = *(const short8*)(xcur + swzX(lrow, (4 * kk + 3) * 64 + kg * 16));
            acc0 = __builtin_amdgcn_mfma_f32_16x16x32_bf16(a0, Bf[4 * kk + 0], acc0, 0, 0, 0);
            acc1 = __builtin_amdgcn_mfma_f32_16x16x32_bf16(a1, Bf[4 * kk + 1], acc1, 0, 0, 0);
            acc2 = __builtin_amdgcn_mfma_f32_16x16x32_bf16(a2, Bf[4 * kk + 2], acc2, 0, 0, 0);
            acc3 = __builtin_amdgcn_mfma_f32_16x16x32_bf16(a3, Bf[4 * kk + 3], acc3, 0, 0, 0);
        }

        // ---- C: counted wait = h loads done (x keeps flying); stage hs[t&1].
        // hs[t&1] was last read at D(t-2): wait done >= t-2. (Also covers G's
        // xs guard done >= t-1 ... no: G checks its own, stronger condition.)
        if (has_next) asm volatile("s_waitcnt vmcnt(8)" ::: "memory");
        else          asm volatile("s_waitcnt vmcnt(0)" ::: "memory");
        __builtin_amdgcn_sched_barrier(0);
        spin_ge(f_dn, t - 2);
        char* hcur = hb + (t & 1) * HSBUFB;
#pragma unroll
        for (int q = 0; q < 8; ++q)
            *(ushort8*)(hcur + swzH(sm, seg * 128 + q * 16)) = hv[q];
        flag_set(&f_sh[wid], t, lane);

        // ---- D: h-MFMA (needs all waves' hs staging of step t) ----
        spin_ge(f_sh, t);
#pragma unroll
        for (int kk = 4; kk < 12; ++kk) {
            short8 a0 = *(const short8*)(hcur + swzH(lrow, (4 * kk - 16 + 0) * 64 + kg * 16));
            short8 a1 = *(const short8*)(hcur + swzH(lrow, (4 * kk - 16 + 1) * 64 + kg * 16));
            short8 a2 = *(const short8*)(hcur + swzH(lrow, (4 * kk - 16 + 2) * 64 + kg * 16));
            short8 a3 = *(const short8*)(hcur + swzH(lrow, (4 * kk - 16 + 3) * 64 + kg * 16));
            acc0 = __builtin_amdgcn_mfma_f32_16x16x32_bf16(a0, Bf[4 * kk + 0], acc0, 0, 0, 0);
            acc1 = __builtin_amdgcn_mfma_f32_16x16x32_bf16(a1, Bf[4 * kk + 1], acc1, 0, 0, 0);
            acc2 = __builtin_amdgcn_mfma_f32_16x16x32_bf16(a2, Bf[4 * kk + 2], acc2, 0, 0, 0);
            acc3 = __builtin_amdgcn_mfma_f32_16x16x32_bf16(a3, Bf[4 * kk + 3], acc3, 0, 0, 0);
        }
        // all my LDS reads of step t are done (lgkm drained) -> publish done=t
        flag_set(&f_dn[wid], t, lane);

        // ---- E: epilogue. C row = kg*4 + r, col = ncol (R0 layout: quarter-
        // wave lanes write 32B-contiguous runs — R6 proved C^T breaks this) ----
        if (!has_next) {
#pragma unroll
            for (int r = 0; r < 4; ++r) {
                float pre = acc0[r] + acc1[r] + acc2[r] + acc3[r] + bias;
                out[(size_t)(g * GROWS + kg * 4 + r) * HDIM + ncol] = fast_tanh(pre);
            }
            break;
        }
        {
            unsigned short* hdst = hbuf + (size_t)slw * HBUF_ELEMS;
#pragma unroll
            for (int r = 0; r < 4; ++r) {
                float pre = acc0[r] + acc1[r] + acc2[r] + acc3[r] + bias;
                float hvf = fast_tanh(pre);
                st_h16_if(hdst + (size_t)(g * GROWS + kg * 4 + r) * HDIM + ncol, f2bf(hvf));
            }
        }

        // ---- F: drain stores (+x loads, long landed) then per-wave publish ----
        asm volatile("s_waitcnt vmcnt(0)" ::: "memory");
        __builtin_amdgcn_sched_barrier(0);
        if (lane == 0) st_u32_if(myflag, (unsigned int)(t + 1));

        // ---- G: stage x(t+1) -> xs[(t+1)&1] (last read at B(t-1); all waves
        // have done >= t-1 per C's spin at this step) then publish stage_x ----
        spin_ge(f_dn, t - 1);
        {
            char* xnxt = xb + ((t + 1) & 1) * XBUFB;
#pragma unroll
            for (int q = 0; q < 4; ++q) {
                float4 a = xv[2 * q], b = xv[2 * q + 1];
                ushort8 w;
                w[0] = f2bf(a.x); w[1] = f2bf(a.y); w[2] = f2bf(a.z); w[3] = f2bf(a.w);
                w[4] = f2bf(b.x); w[5] = f2bf(b.y); w[6] = f2bf(b.z); w[7] = f2bf(b.w);
                *(ushort8*)(xnxt + swzX(sm, seg * 64 + q * 16)) = w;
            }
        }
        flag_set(&f_sx[wid], t + 1, lane);
        sl = slw;
    }
}

// ---------------------------------------------------------------------------
extern "C" void kernel_launch(void* const* d_in, const int* in_sizes, int n_in,
                              void* d_out, int out_size, void* d_ws, size_t ws_size,
                              hipStream_t stream) {
    const float* x  = (const float*)d_in[0];
    const float* h0 = (const float*)d_in[1];
    const float* Wx = (const float*)d_in[2];
    const float* bx = (const float*)d_in[3];
    const float* Wh = (const float*)d_in[4];
    const float* bh = (const float*)d_in[5];
    float* out = (float*)d_out;

    // workspace layout (128B-aligned pieces)
    const size_t OFF_WT = 0;                    // 1024*1536 bf16 = 3,145,728 B
    const size_t OFF_BS = 3145728;              // 1024 f32 = 4096 B
    const size_t OFF_HB = 3149824;              // 3*128*1024 bf16 = 786,432 B
    const size_t OFF_FL = 3936256;              // 512 u32 packed flags = 2048 B
    const size_t WS_NEED = 3938304;
    if (ws_size < WS_NEED) {                    // diagnostic: absmax ~1e6 => ws too small
        hipLaunchKernelGGL(ws_fail_kernel, dim3(1), dim3(1), 0, stream, out);
        return;
    }

    unsigned short* WT    = (unsigned short*)((char*)d_ws + OFF_WT);
    float*          bsum  = (float*)((char*)d_ws + OFF_BS);
    unsigned short* hbuf  = (unsigned short*)((char*)d_ws + OFF_HB);
    unsigned int*   flags = (unsigned int*)((char*)d_ws + OFF_FL);

    prep_transpose<<<dim3(IDIM / 32, HDIM / 32), dim3(32, 8), 0, stream>>>(Wx, WT, 0);
    prep_transpose<<<dim3(HDIM / 32, HDIM / 32), dim3(32, 8), 0, stream>>>(Wh, WT, IDIM);
    const int misc_total = HBUF_ELEMS + HDIM + NFLAG;
    prep_misc<<<dim3((misc_total + 255) / 256), dim3(256), 0, stream>>>(
        h0, bx, bh, bsum, hbuf, flags);
    rnn_fused<<<dim3(NGROUP * NCB), dim3(256), 0, stream>>>(
        x, WT, bsum, hbuf, flags, out);
}

// Round 8
// 1987.184 us; speedup vs baseline: 1.4760x; 1.4760x over previous
//
#include <hip/hip_runtime.h>
#include <hip/hip_bf16.h>

typedef __attribute__((ext_vector_type(4))) float f32x4;
typedef __attribute__((ext_vector_type(8))) short short8;
typedef __attribute__((ext_vector_type(8))) unsigned short ushort8;

#define T_STEPS 512
#define BATCH   128
#define IDIM    512
#define HDIM    1024
#define KTOT    1536           // IDIM + HDIM (fused [x_t | h] @ [Wx; Wh])
#define NGROUP  8              // batch groups (16 rows each)
#define GROWS   16             // batch rows per group
#define NCB     16             // column-blocks per group
#define CBW     64             // output columns per block (4 waves x 16)
#define NBLK    (NGROUP * NCB) // 128 blocks
#define HBUF_ELEMS (BATCH * HDIM)
#define XBUFB   (GROWS * IDIM * 2)   // bytes per xs half
#define NFLAG   (NGROUP * 64)        // per-WAVE flags, packed 4B (coalesced polls)
// handshake scratch appended after flags: xcdmap[NBLK], hsflag[NBLK]

// f32 -> bf16 round-to-nearest-even
__device__ __forceinline__ unsigned short f2bf(float f) {
    unsigned int u = __builtin_bit_cast(unsigned int, f);
    u = (u + 0x7FFFu + ((u >> 16) & 1u)) >> 16;
    return (unsigned short)u;
}

// fast tanh: clamp +-9, e2x = exp2(2*log2e*x), (e2x-1)*rcp(e2x+1).
__device__ __forceinline__ float fast_tanh(float x) {
    x = fminf(9.0f, fmaxf(-9.0f, x));
    float t = __builtin_exp2f(x * 2.8853900817779268f);
    return (t - 1.0f) * __builtin_amdgcn_rcpf(t + 1.0f);
}

// XOR swizzles (row strides 0 mod 128B; XOR row low-bits into the 16B-slot index)
__device__ __forceinline__ int swzX(int row, int c) { return row * 1024 + (c ^ ((row & 7) << 4)); }
__device__ __forceinline__ int swzH(int row, int c) { return row * 2048 + (c ^ ((row & 7) << 4)); }

// ---- coherence primitives ---------------------------------------------------
// Session model (R0-R7 counters): sc0 sc1 STORES write through to HBM
// (WRITE_SIZE == h-store bytes) => F's vmcnt(0) drain pays an HBM ack
// (~1100cy), the largest removable chain link. PLAIN stores are L1-write-
// through -> dirty in the shared same-XCD L2, vmcnt ack ~250cy, and the
// consumer's sc0 sc1 h-load (L1-bypass, proven) dirty-hits that L2 line.
// Valid ONLY same-XCD => gated by the R1 handshake (completed on HW).
// Poll/flag path stays sc0 sc1 in BOTH templates (proven; no new hang mode —
// a wrong data-freshness assumption shows as absmax fail, not deadlock).
__device__ __forceinline__ void st_u32_if(unsigned int* p, unsigned int v) {
    asm volatile("global_store_dword %0, %1, off sc0 sc1" :: "v"(p), "v"(v) : "memory");
}
template<bool FAST>
__device__ __forceinline__ void st_h16_c(unsigned short* p, unsigned short v) {
    if (FAST) asm volatile("global_store_short %0, %1, off" :: "v"(p), "v"(v) : "memory");
    else      asm volatile("global_store_short %0, %1, off sc0 sc1" :: "v"(p), "v"(v) : "memory");
}
__device__ __forceinline__ unsigned int ld_u32_if(const unsigned int* p) {
    unsigned int v;
    asm volatile("global_load_dword %0, %1, off sc0 sc1\n\ts_waitcnt vmcnt(0)"
                 : "=v"(v) : "v"(p) : "memory");
    return v;
}
// issue 8 pipelined dwordx4 h-tile loads (128 B), NO wait (drained by counted vmcnt)
__device__ __forceinline__ void ldh_issue_if(const unsigned short* p, ushort8 v[8]) {
    asm volatile(
        "global_load_dwordx4 %0, %8, off sc0 sc1\n\t"
        "global_load_dwordx4 %1, %8, off offset:16 sc0 sc1\n\t"
        "global_load_dwordx4 %2, %8, off offset:32 sc0 sc1\n\t"
        "global_load_dwordx4 %3, %8, off offset:48 sc0 sc1\n\t"
        "global_load_dwordx4 %4, %8, off offset:64 sc0 sc1\n\t"
        "global_load_dwordx4 %5, %8, off offset:80 sc0 sc1\n\t"
        "global_load_dwordx4 %6, %8, off offset:96 sc0 sc1\n\t"
        "global_load_dwordx4 %7, %8, off offset:112 sc0 sc1"
        : "=&v"(v[0]), "=&v"(v[1]), "=&v"(v[2]), "=&v"(v[3]),
          "=&v"(v[4]), "=&v"(v[5]), "=&v"(v[6]), "=&v"(v[7])
        : "v"(p) : "memory");
}
// issue 8 pipelined dwordx4 x-tile loads (128 B of f32), normal caching, NO wait
__device__ __forceinline__ void ldx_issue(const float* p, float4 v[8]) {
    asm volatile(
        "global_load_dwordx4 %0, %8, off\n\t"
        "global_load_dwordx4 %1, %8, off offset:16\n\t"
        "global_load_dwordx4 %2, %8, off offset:32\n\t"
        "global_load_dwordx4 %3, %8, off offset:48\n\t"
        "global_load_dwordx4 %4, %8, off offset:64\n\t"
        "global_load_dwordx4 %5, %8, off offset:80\n\t"
        "global_load_dwordx4 %6, %8, off offset:96\n\t"
        "global_load_dwordx4 %7, %8, off offset:112"
        : "=&v"(v[0]), "=&v"(v[1]), "=&v"(v[2]), "=&v"(v[3]),
          "=&v"(v[4]), "=&v"(v[5]), "=&v"(v[6]), "=&v"(v[7])
        : "v"(p) : "memory");
}

// ---------------------------------------------------------------------------
// Prep: WT[n][k] = bf16(W[k][n]) for W in {Wx (koff=0), Wh (koff=IDIM)}.
__global__ void prep_transpose(const float* __restrict__ src,
                               unsigned short* __restrict__ dst, int koff) {
    __shared__ float tl[32][33];
    const int tx = threadIdx.x, ty = threadIdx.y;
    const int k0 = blockIdx.x * 32, n0 = blockIdx.y * 32;
#pragma unroll
    for (int q = 0; q < 4; ++q) {
        int kk = ty * 4 + q;
        tl[kk][tx] = src[(size_t)(k0 + kk) * HDIM + n0 + tx];
    }
    __syncthreads();
#pragma unroll
    for (int q = 0; q < 4; ++q) {
        int nn = ty * 4 + q;
        dst[(size_t)(n0 + nn) * KTOT + koff + k0 + tx] = f2bf(tl[tx][nn]);
    }
}

// Prep: hbuf slot0=bf16(h0); bsum=bx+bh; flags+handshake scratch=0. Dispatch-
// end release flushes all L2s before rnn_fused (stream order) — unchanged.
__global__ void prep_misc(const float* __restrict__ h0, const float* __restrict__ bx,
                          const float* __restrict__ bh, float* __restrict__ bsum,
                          unsigned short* __restrict__ hbuf, unsigned int* __restrict__ flags) {
    int idx = blockIdx.x * 256 + threadIdx.x;
    if (idx < HBUF_ELEMS) {
        hbuf[idx] = f2bf(h0[idx]);
    } else if (idx < HBUF_ELEMS + HDIM) {
        int j = idx - HBUF_ELEMS;
        bsum[j] = bx[j] + bh[j];
    } else if (idx < HBUF_ELEMS + HDIM + NFLAG + 2 * NBLK) {
        flags[idx - HBUF_ELEMS - HDIM] = 0;
    }
}

__global__ void ws_fail_kernel(float* out) { out[0] = 1.0e6f; }  // ws_size diagnostic

// ---------------------------------------------------------------------------
// R0 loop VERBATIM except the h-data store scope (template). Iteration: A0
// quartet poll -> A h+x load issue -> B x-MFMA -> C vmcnt(8)+stage+barrier ->
// D h-MFMA -> E tanh + 4x2B h stores (R6: this layout coalesces best) ->
// F vmcnt(0) drain (FAST: L2 ack ~250cy vs HBM ~1100cy) + flag publish ->
// G x-stage -> barrier.
template<bool FAST>
__device__ __forceinline__ void rnn_loop(
        const float* __restrict__ x, const unsigned short* __restrict__ WT,
        const float* __restrict__ bsum, unsigned short* __restrict__ hbuf,
        unsigned int* __restrict__ flags, float* __restrict__ out,
        unsigned short* xs, unsigned short* hs, const int tid, const int bid) {
    char* xb = (char*)xs;
    char* hb = (char*)hs;
    const int g    = bid & 7;
    const int cb   = bid >> 3;
    const int lane = tid & 63;
    const int wid  = tid >> 6;
    const int lrow = lane & 15;    // A row / C col low bits
    const int kg   = lane >> 4;    // k-group 0..3
    const int ncol = cb * CBW + wid * 16 + lrow;

    // Resident B fragments: lane holds WT[ncol][kc*32 + kg*8 .. +7]
    short8 Bf[48];
    {
        const short8* wp = (const short8*)(WT + (size_t)ncol * KTOT);
#pragma unroll
        for (int kc = 0; kc < 48; ++kc) Bf[kc] = wp[kc * 4 + kg];
    }
#pragma unroll
    for (int kc = 0; kc < 48; ++kc) asm volatile("" : "+v"(Bf[kc]));
    const float bias = bsum[ncol];

    const int sm  = tid & 15;      // staged row 0..15
    const int seg = tid >> 4;      // 1/16 of the row
    unsigned int* const myflag = &flags[(g << 6) + (cb << 2) + wid];
    // wave w's staged columns come from producer blocks 4w..4w+3 only:
    // lane checks flag of producer block (wid*4 + lane>>4), wave sub-flag lane&3
    const unsigned int* const pollp =
        &flags[(g << 6) + (((wid << 2) + (lane >> 4)) << 2) + (lane & 3)];
    const size_t rowoff = (size_t)(g * GROWS + sm) * HDIM + seg * 64;

    // ---- prologue: stage x(0) into xs buf 0 (deterministic queue: drain) ----
    {
        float4 xv0[8];
        ldx_issue(x + ((size_t)g * GROWS + sm) * IDIM + seg * 32, xv0);
        asm volatile("s_waitcnt vmcnt(0)" ::: "memory");
        __builtin_amdgcn_sched_barrier(0);
#pragma unroll
        for (int q = 0; q < 4; ++q) {
            float4 a = xv0[2 * q], b = xv0[2 * q + 1];
            ushort8 w;
            w[0] = f2bf(a.x); w[1] = f2bf(a.y); w[2] = f2bf(a.z); w[3] = f2bf(a.w);
            w[4] = f2bf(b.x); w[5] = f2bf(b.y); w[6] = f2bf(b.z); w[7] = f2bf(b.w);
            *(ushort8*)(xb + swzX(sm, seg * 64 + q * 16)) = w;
        }
        asm volatile("s_waitcnt lgkmcnt(0)" ::: "memory");
        __builtin_amdgcn_s_barrier();
        __builtin_amdgcn_sched_barrier(0);
    }

    for (int t = 0; t < T_STEPS; ++t) {
        const bool has_next = (t + 1 < T_STEPS);

        // ---- A0: per-wave quartet poll (flags carry value t after F(t-1)) ----
        {
            const unsigned int tgt = (unsigned int)t;
            while (true) {
                unsigned int v = ld_u32_if(pollp);
                if (__all(v >= tgt)) break;    // no s_sleep: vmcnt RT paces the loop
            }
        }

        // ---- A: issue h(t) loads FIRST (oldest in queue), then x(t+1) ----
        ushort8 hv[8];
        ldh_issue_if(hbuf + (size_t)(t & 1) * HBUF_ELEMS + rowoff, hv);
        float4 xv[8];
        if (has_next)
            ldx_issue(x + ((size_t)(t + 1) * BATCH + g * GROWS + sm) * IDIM + seg * 32, xv);

        // ---- B: x-side MFMA (kc 0..15) under the h/x load latency ----
        const char* xcur = xb + (t & 1) * XBUFB;
        f32x4 acc0 = {0.f, 0.f, 0.f, 0.f}, acc1 = acc0, acc2 = acc0, acc3 = acc0;
#pragma unroll
        for (int kk = 0; kk < 4; ++kk) {
            short8 a0 = *(const short8*)(xcur + swzX(lrow, (4 * kk + 0) * 64 + kg * 16));
            short8 a1 = *(const short8*)(xcur + swzX(lrow, (4 * kk + 1) * 64 + kg * 16));
            short8 a2 = *(const short8*)(xcur + swzX(lrow, (4 * kk + 2) * 64 + kg * 16));
            short8 a3 = *(const short8*)(xcur + swzX(lrow, (4 * kk + 3) * 64 + kg * 16));
            acc0 = __builtin_amdgcn_mfma_f32_16x16x32_bf16(a0, Bf[4 * kk + 0], acc0, 0, 0, 0);
            acc1 = __builtin_amdgcn_mfma_f32_16x16x32_bf16(a1, Bf[4 * kk + 1], acc1, 0, 0, 0);
            acc2 = __builtin_amdgcn_mfma_f32_16x16x32_bf16(a2, Bf[4 * kk + 2], acc2, 0, 0, 0);
            acc3 = __builtin_amdgcn_mfma_f32_16x16x32_bf16(a3, Bf[4 * kk + 3], acc3, 0, 0, 0);
        }

        // ---- C: counted wait = h loads done, x loads keep flying ----
        if (has_next) asm volatile("s_waitcnt vmcnt(8)" ::: "memory");
        else          asm volatile("s_waitcnt vmcnt(0)" ::: "memory");
        __builtin_amdgcn_sched_barrier(0);
#pragma unroll
        for (int q = 0; q < 8; ++q)
            *(ushort8*)(hb + swzH(sm, seg * 128 + q * 16)) = hv[q];
        asm volatile("s_waitcnt lgkmcnt(0)" ::: "memory");
        __builtin_amdgcn_s_barrier();          // raw: no auto vmcnt(0) drain
        __builtin_amdgcn_sched_barrier(0);

        // ---- D: h-side MFMA (kc 16..47) ----
#pragma unroll
        for (int kk = 4; kk < 12; ++kk) {
            short8 a0 = *(const short8*)(hb + swzH(lrow, (4 * kk - 16 + 0) * 64 + kg * 16));
            short8 a1 = *(const short8*)(hb + swzH(lrow, (4 * kk - 16 + 1) * 64 + kg * 16));
            short8 a2 = *(const short8*)(hb + swzH(lrow, (4 * kk - 16 + 2) * 64 + kg * 16));
            short8 a3 = *(const short8*)(hb + swzH(lrow, (4 * kk - 16 + 3) * 64 + kg * 16));
            acc0 = __builtin_amdgcn_mfma_f32_16x16x32_bf16(a0, Bf[4 * kk + 0], acc0, 0, 0, 0);
            acc1 = __builtin_amdgcn_mfma_f32_16x16x32_bf16(a1, Bf[4 * kk + 1], acc1, 0, 0, 0);
            acc2 = __builtin_amdgcn_mfma_f32_16x16x32_bf16(a2, Bf[4 * kk + 2], acc2, 0, 0, 0);
            acc3 = __builtin_amdgcn_mfma_f32_16x16x32_bf16(a3, Bf[4 * kk + 3], acc3, 0, 0, 0);
        }

        // ---- E: epilogue. C row = kg*4 + r, col = ncol (R0 layout: quarter-
        // wave lanes write 32B-contiguous runs; R6 proved C^T packing worse) ----
        if (!has_next) {
#pragma unroll
            for (int r = 0; r < 4; ++r) {
                float pre = acc0[r] + acc1[r] + acc2[r] + acc3[r] + bias;
                out[(size_t)(g * GROWS + kg * 4 + r) * HDIM + ncol] = fast_tanh(pre);
            }
            break;
        }
        {
            unsigned short* hdst = hbuf + (size_t)((t + 1) & 1) * HBUF_ELEMS;
#pragma unroll
            for (int r = 0; r < 4; ++r) {
                float pre = acc0[r] + acc1[r] + acc2[r] + acc3[r] + bias;
                float hvf = fast_tanh(pre);
                st_h16_c<FAST>(hdst + (size_t)(g * GROWS + kg * 4 + r) * HDIM + ncol, f2bf(hvf));
            }
        }

        // ---- F: drain stores (FAST: L2 ack, the cut) then per-wave publish ----
        asm volatile("s_waitcnt vmcnt(0)" ::: "memory");
        __builtin_amdgcn_sched_barrier(0);
        if (lane == 0) st_u32_if(myflag, (unsigned int)(t + 1));

        // ---- G: stage x(t+1) regs -> xs[(t+1)&1] (no waits) ----
        {
            char* xnxt = xb + ((t + 1) & 1) * XBUFB;
#pragma unroll
            for (int q = 0; q < 4; ++q) {
                float4 a = xv[2 * q], b = xv[2 * q + 1];
                ushort8 w;
                w[0] = f2bf(a.x); w[1] = f2bf(a.y); w[2] = f2bf(a.z); w[3] = f2bf(a.w);
                w[4] = f2bf(b.x); w[5] = f2bf(b.y); w[6] = f2bf(b.z); w[7] = f2bf(b.w);
                *(ushort8*)(xnxt + swzX(sm, seg * 64 + q * 16)) = w;
            }
        }

        // ---- loop end: hs/xs reuse guard ----
        asm volatile("s_waitcnt lgkmcnt(0)" ::: "memory");
        __builtin_amdgcn_s_barrier();
        __builtin_amdgcn_sched_barrier(0);
    }
}

// ---------------------------------------------------------------------------
// Handshake (R1 structure, completed on HW): exchange HW_REG_XCC_ID via the
// proven sc0 sc1 path; all 128 blocks co-resident (1 block/CU). If a group's
// 16 blocks share an XCD -> FAST (plain h stores, L2-ack drain); else exact-R0
// SLOW path (correct under arbitrary XCD assignment, Guideline 16).
__global__ __launch_bounds__(256, 1) void rnn_fused(
        const float* __restrict__ x, const unsigned short* __restrict__ WT,
        const float* __restrict__ bsum, unsigned short* __restrict__ hbuf,
        unsigned int* __restrict__ flags, float* __restrict__ out) {
    __shared__ unsigned short xs[2 * GROWS * IDIM];   // 32 KB (double-buffered x tile)
    __shared__ unsigned short hs[GROWS * HDIM];       // 32 KB (h tile)
    const int tid  = threadIdx.x;
    const int bid  = blockIdx.x;
    const int g    = bid & 7;
    const int lane = tid & 63;

    unsigned int myxcd;
    asm volatile("s_getreg_b32 %0, hwreg(HW_REG_XCC_ID)" : "=s"(myxcd));
    unsigned int* const xcdmap = flags + NFLAG;          // [NBLK]
    unsigned int* const hsflag = flags + NFLAG + NBLK;   // [NBLK]
    if (tid == 0) {
        st_u32_if(&xcdmap[bid], myxcd + 1u);
        asm volatile("s_waitcnt vmcnt(0)" ::: "memory");
        st_u32_if(&hsflag[bid], 1u);
    }
    // peers of group g are bids g, g+8, ..., g+120; lanes 16..63 duplicate
    const int peer = g + 8 * (lane & 15);
    while (true) {
        unsigned int v = ld_u32_if(&hsflag[peer]);
        if (__all(v != 0)) break;
    }
    const unsigned int px = ld_u32_if(&xcdmap[peer]);
    // verdict symmetric across the group (same 16 values) -> same path chosen
    if (__all(px == myxcd + 1u))
        rnn_loop<true >(x, WT, bsum, hbuf, flags, out, xs, hs, tid, bid);
    else
        rnn_loop<false>(x, WT, bsum, hbuf, flags, out, xs, hs, tid, bid);
}

// ---------------------------------------------------------------------------
extern "C" void kernel_launch(void* const* d_in, const int* in_sizes, int n_in,
                              void* d_out, int out_size, void* d_ws, size_t ws_size,
                              hipStream_t stream) {
    const float* x  = (const float*)d_in[0];
    const float* h0 = (const float*)d_in[1];
    const float* Wx = (const float*)d_in[2];
    const float* bx = (const float*)d_in[3];
    const float* Wh = (const float*)d_in[4];
    const float* bh = (const float*)d_in[5];
    float* out = (float*)d_out;

    // workspace layout (128B-aligned pieces)
    const size_t OFF_WT = 0;                    // 1024*1536 bf16 = 3,145,728 B
    const size_t OFF_BS = 3145728;              // 1024 f32 = 4096 B
    const size_t OFF_HB = 3149824;              // 2*128*1024 bf16 = 524,288 B
    const size_t OFF_FL = 3674112;              // (512 + 256) u32 = 3072 B
    const size_t WS_NEED = 3677184;
    if (ws_size < WS_NEED) {                    // diagnostic: absmax ~1e6 => ws too small
        hipLaunchKernelGGL(ws_fail_kernel, dim3(1), dim3(1), 0, stream, out);
        return;
    }

    unsigned short* WT    = (unsigned short*)((char*)d_ws + OFF_WT);
    float*          bsum  = (float*)((char*)d_ws + OFF_BS);
    unsigned short* hbuf  = (unsigned short*)((char*)d_ws + OFF_HB);
    unsigned int*   flags = (unsigned int*)((char*)d_ws + OFF_FL);

    prep_transpose<<<dim3(IDIM / 32, HDIM / 32), dim3(32, 8), 0, stream>>>(Wx, WT, 0);
    prep_transpose<<<dim3(HDIM / 32, HDIM / 32), dim3(32, 8), 0, stream>>>(Wh, WT, IDIM);
    const int misc_total = HBUF_ELEMS + HDIM + NFLAG + 2 * NBLK;
    prep_misc<<<dim3((misc_total + 255) / 256), dim3(256), 0, stream>>>(
        h0, bx, bh, bsum, hbuf, flags);
    rnn_fused<<<dim3(NBLK), dim3(256), 0, stream>>>(
        x, WT, bsum, hbuf, flags, out);
}

// Round 9
// 1600.634 us; speedup vs baseline: 1.8324x; 1.2415x over previous
//
#include <hip/hip_runtime.h>
#include <hip/hip_bf16.h>

typedef __attribute__((ext_vector_type(4))) float f32x4;
typedef __attribute__((ext_vector_type(8))) short short8;
typedef __attribute__((ext_vector_type(8))) unsigned short ushort8;

#define T_STEPS 512
#define BATCH   128
#define IDIM    512
#define HDIM    1024
#define KTOT    1536           // IDIM + HDIM (fused [x_t | h] @ [Wx; Wh])
#define NGROUP  8              // batch groups (16 rows each)
#define GROWS   16             // batch rows per group
#define NCB     16             // column-blocks per group
#define CBW     64             // output columns per block (4 waves x 16)
#define NBLK    (NGROUP * NCB) // 128 blocks
#define HBUF_ELEMS (BATCH * HDIM)
#define XBUFB   (GROWS * IDIM * 2)   // bytes per xs half
#define NFLAG   (NGROUP * 64)        // per-WAVE flags, packed 4B (coalesced polls)
// handshake scratch appended after flags: xcdmap[NBLK], hsflag[NBLK]

// f32 -> bf16 round-to-nearest-even
__device__ __forceinline__ unsigned short f2bf(float f) {
    unsigned int u = __builtin_bit_cast(unsigned int, f);
    u = (u + 0x7FFFu + ((u >> 16) & 1u)) >> 16;
    return (unsigned short)u;
}

// fast tanh: clamp +-9, e2x = exp2(2*log2e*x), (e2x-1)*rcp(e2x+1).
__device__ __forceinline__ float fast_tanh(float x) {
    x = fminf(9.0f, fmaxf(-9.0f, x));
    float t = __builtin_exp2f(x * 2.8853900817779268f);
    return (t - 1.0f) * __builtin_amdgcn_rcpf(t + 1.0f);
}

// XOR swizzles (row strides 0 mod 128B; XOR row low-bits into the 16B-slot index)
__device__ __forceinline__ int swzX(int row, int c) { return row * 1024 + (c ^ ((row & 7) << 4)); }
__device__ __forceinline__ int swzH(int row, int c) { return row * 2048 + (c ^ ((row & 7) << 4)); }

// ---- coherence primitives ---------------------------------------------------
// Session model (validated R8): sc0 sc1 STORES write through to HBM and their
// vmcnt ack costs ~1100cy; PLAIN stores ack at the shared same-XCD L2
// (~250cy) and sc0 sc1 (L1-bypassing) consumer loads dirty-hit that line —
// R8 proved this end-to-end for h-data (WRITE_SIZE 139.5->9.2MB, -182us,
// absmax clean). R9: apply the SAME mechanism to the per-step flag publish —
// the A0 poll's vmcnt(0) drains the producer's own flag store, so its HBM ack
// sits at the head of every step. FAST requires same-XCD (R1-handshake-gated);
// SLOW path keeps everything sc0 sc1 (exact R0).
__device__ __forceinline__ void st_u32_if(unsigned int* p, unsigned int v) {
    asm volatile("global_store_dword %0, %1, off sc0 sc1" :: "v"(p), "v"(v) : "memory");
}
template<bool FAST>
__device__ __forceinline__ void st_u32_c(unsigned int* p, unsigned int v) {
    if (FAST) asm volatile("global_store_dword %0, %1, off" :: "v"(p), "v"(v) : "memory");
    else      asm volatile("global_store_dword %0, %1, off sc0 sc1" :: "v"(p), "v"(v) : "memory");
}
template<bool FAST>
__device__ __forceinline__ void st_h16_c(unsigned short* p, unsigned short v) {
    if (FAST) asm volatile("global_store_short %0, %1, off" :: "v"(p), "v"(v) : "memory");
    else      asm volatile("global_store_short %0, %1, off sc0 sc1" :: "v"(p), "v"(v) : "memory");
}
__device__ __forceinline__ unsigned int ld_u32_if(const unsigned int* p) {
    unsigned int v;
    asm volatile("global_load_dword %0, %1, off sc0 sc1\n\ts_waitcnt vmcnt(0)"
                 : "=v"(v) : "v"(p) : "memory");
    return v;
}
// issue 8 pipelined dwordx4 h-tile loads (128 B), NO wait (drained by counted vmcnt)
__device__ __forceinline__ void ldh_issue_if(const unsigned short* p, ushort8 v[8]) {
    asm volatile(
        "global_load_dwordx4 %0, %8, off sc0 sc1\n\t"
        "global_load_dwordx4 %1, %8, off offset:16 sc0 sc1\n\t"
        "global_load_dwordx4 %2, %8, off offset:32 sc0 sc1\n\t"
        "global_load_dwordx4 %3, %8, off offset:48 sc0 sc1\n\t"
        "global_load_dwordx4 %4, %8, off offset:64 sc0 sc1\n\t"
        "global_load_dwordx4 %5, %8, off offset:80 sc0 sc1\n\t"
        "global_load_dwordx4 %6, %8, off offset:96 sc0 sc1\n\t"
        "global_load_dwordx4 %7, %8, off offset:112 sc0 sc1"
        : "=&v"(v[0]), "=&v"(v[1]), "=&v"(v[2]), "=&v"(v[3]),
          "=&v"(v[4]), "=&v"(v[5]), "=&v"(v[6]), "=&v"(v[7])
        : "v"(p) : "memory");
}
// issue 8 pipelined dwordx4 x-tile loads (128 B of f32), normal caching, NO wait
__device__ __forceinline__ void ldx_issue(const float* p, float4 v[8]) {
    asm volatile(
        "global_load_dwordx4 %0, %8, off\n\t"
        "global_load_dwordx4 %1, %8, off offset:16\n\t"
        "global_load_dwordx4 %2, %8, off offset:32\n\t"
        "global_load_dwordx4 %3, %8, off offset:48\n\t"
        "global_load_dwordx4 %4, %8, off offset:64\n\t"
        "global_load_dwordx4 %5, %8, off offset:80\n\t"
        "global_load_dwordx4 %6, %8, off offset:96\n\t"
        "global_load_dwordx4 %7, %8, off offset:112"
        : "=&v"(v[0]), "=&v"(v[1]), "=&v"(v[2]), "=&v"(v[3]),
          "=&v"(v[4]), "=&v"(v[5]), "=&v"(v[6]), "=&v"(v[7])
        : "v"(p) : "memory");
}

// ---------------------------------------------------------------------------
// Prep: WT[n][k] = bf16(W[k][n]) for W in {Wx (koff=0), Wh (koff=IDIM)}.
__global__ void prep_transpose(const float* __restrict__ src,
                               unsigned short* __restrict__ dst, int koff) {
    __shared__ float tl[32][33];
    const int tx = threadIdx.x, ty = threadIdx.y;
    const int k0 = blockIdx.x * 32, n0 = blockIdx.y * 32;
#pragma unroll
    for (int q = 0; q < 4; ++q) {
        int kk = ty * 4 + q;
        tl[kk][tx] = src[(size_t)(k0 + kk) * HDIM + n0 + tx];
    }
    __syncthreads();
#pragma unroll
    for (int q = 0; q < 4; ++q) {
        int nn = ty * 4 + q;
        dst[(size_t)(n0 + nn) * KTOT + koff + k0 + tx] = f2bf(tl[tx][nn]);
    }
}

// Prep: hbuf slot0=bf16(h0); bsum=bx+bh; flags+handshake scratch=0. Dispatch-
// end release flushes all L2s before rnn_fused (stream order) — unchanged.
__global__ void prep_misc(const float* __restrict__ h0, const float* __restrict__ bx,
                          const float* __restrict__ bh, float* __restrict__ bsum,
                          unsigned short* __restrict__ hbuf, unsigned int* __restrict__ flags) {
    int idx = blockIdx.x * 256 + threadIdx.x;
    if (idx < HBUF_ELEMS) {
        hbuf[idx] = f2bf(h0[idx]);
    } else if (idx < HBUF_ELEMS + HDIM) {
        int j = idx - HBUF_ELEMS;
        bsum[j] = bx[j] + bh[j];
    } else if (idx < HBUF_ELEMS + HDIM + NFLAG + 2 * NBLK) {
        flags[idx - HBUF_ELEMS - HDIM] = 0;
    }
}

__global__ void ws_fail_kernel(float* out) { out[0] = 1.0e6f; }  // ws_size diagnostic

// ---------------------------------------------------------------------------
// R8 loop VERBATIM except the flag-publish store scope (template, same as h).
// Iteration: A0 quartet poll -> A h+x load issue -> B x-MFMA -> C vmcnt(8)+
// stage+barrier -> D h-MFMA -> E tanh + 4x2B h stores (plain in FAST) ->
// F vmcnt(0) drain (L2 ack) + flag publish (NOW plain in FAST: its ack is
// drained by the next poll's vmcnt(0), head-of-step) -> G x-stage -> barrier.
template<bool FAST>
__device__ __forceinline__ void rnn_loop(
        const float* __restrict__ x, const unsigned short* __restrict__ WT,
        const float* __restrict__ bsum, unsigned short* __restrict__ hbuf,
        unsigned int* __restrict__ flags, float* __restrict__ out,
        unsigned short* xs, unsigned short* hs, const int tid, const int bid) {
    char* xb = (char*)xs;
    char* hb = (char*)hs;
    const int g    = bid & 7;
    const int cb   = bid >> 3;
    const int lane = tid & 63;
    const int wid  = tid >> 6;
    const int lrow = lane & 15;    // A row / C col low bits
    const int kg   = lane >> 4;    // k-group 0..3
    const int ncol = cb * CBW + wid * 16 + lrow;

    // Resident B fragments: lane holds WT[ncol][kc*32 + kg*8 .. +7]
    short8 Bf[48];
    {
        const short8* wp = (const short8*)(WT + (size_t)ncol * KTOT);
#pragma unroll
        for (int kc = 0; kc < 48; ++kc) Bf[kc] = wp[kc * 4 + kg];
    }
#pragma unroll
    for (int kc = 0; kc < 48; ++kc) asm volatile("" : "+v"(Bf[kc]));
    const float bias = bsum[ncol];

    const int sm  = tid & 15;      // staged row 0..15
    const int seg = tid >> 4;      // 1/16 of the row
    unsigned int* const myflag = &flags[(g << 6) + (cb << 2) + wid];
    // wave w's staged columns come from producer blocks 4w..4w+3 only:
    // lane checks flag of producer block (wid*4 + lane>>4), wave sub-flag lane&3
    const unsigned int* const pollp =
        &flags[(g << 6) + (((wid << 2) + (lane >> 4)) << 2) + (lane & 3)];
    const size_t rowoff = (size_t)(g * GROWS + sm) * HDIM + seg * 64;

    // ---- prologue: stage x(0) into xs buf 0 (deterministic queue: drain) ----
    {
        float4 xv0[8];
        ldx_issue(x + ((size_t)g * GROWS + sm) * IDIM + seg * 32, xv0);
        asm volatile("s_waitcnt vmcnt(0)" ::: "memory");
        __builtin_amdgcn_sched_barrier(0);
#pragma unroll
        for (int q = 0; q < 4; ++q) {
            float4 a = xv0[2 * q], b = xv0[2 * q + 1];
            ushort8 w;
            w[0] = f2bf(a.x); w[1] = f2bf(a.y); w[2] = f2bf(a.z); w[3] = f2bf(a.w);
            w[4] = f2bf(b.x); w[5] = f2bf(b.y); w[6] = f2bf(b.z); w[7] = f2bf(b.w);
            *(ushort8*)(xb + swzX(sm, seg * 64 + q * 16)) = w;
        }
        asm volatile("s_waitcnt lgkmcnt(0)" ::: "memory");
        __builtin_amdgcn_s_barrier();
        __builtin_amdgcn_sched_barrier(0);
    }

    for (int t = 0; t < T_STEPS; ++t) {
        const bool has_next = (t + 1 < T_STEPS);

        // ---- A0: per-wave quartet poll (flags carry value t after F(t-1)) ----
        {
            const unsigned int tgt = (unsigned int)t;
            while (true) {
                unsigned int v = ld_u32_if(pollp);
                if (__all(v >= tgt)) break;    // no s_sleep: vmcnt RT paces the loop
            }
        }

        // ---- A: issue h(t) loads FIRST (oldest in queue), then x(t+1) ----
        ushort8 hv[8];
        ldh_issue_if(hbuf + (size_t)(t & 1) * HBUF_ELEMS + rowoff, hv);
        float4 xv[8];
        if (has_next)
            ldx_issue(x + ((size_t)(t + 1) * BATCH + g * GROWS + sm) * IDIM + seg * 32, xv);

        // ---- B: x-side MFMA (kc 0..15) under the h/x load latency ----
        const char* xcur = xb + (t & 1) * XBUFB;
        f32x4 acc0 = {0.f, 0.f, 0.f, 0.f}, acc1 = acc0, acc2 = acc0, acc3 = acc0;
#pragma unroll
        for (int kk = 0; kk < 4; ++kk) {
            short8 a0 = *(const short8*)(xcur + swzX(lrow, (4 * kk + 0) * 64 + kg * 16));
            short8 a1 = *(const short8*)(xcur + swzX(lrow, (4 * kk + 1) * 64 + kg * 16));
            short8 a2 = *(const short8*)(xcur + swzX(lrow, (4 * kk + 2) * 64 + kg * 16));
            short8 a3 = *(const short8*)(xcur + swzX(lrow, (4 * kk + 3) * 64 + kg * 16));
            acc0 = __builtin_amdgcn_mfma_f32_16x16x32_bf16(a0, Bf[4 * kk + 0], acc0, 0, 0, 0);
            acc1 = __builtin_amdgcn_mfma_f32_16x16x32_bf16(a1, Bf[4 * kk + 1], acc1, 0, 0, 0);
            acc2 = __builtin_amdgcn_mfma_f32_16x16x32_bf16(a2, Bf[4 * kk + 2], acc2, 0, 0, 0);
            acc3 = __builtin_amdgcn_mfma_f32_16x16x32_bf16(a3, Bf[4 * kk + 3], acc3, 0, 0, 0);
        }

        // ---- C: counted wait = h loads done, x loads keep flying ----
        if (has_next) asm volatile("s_waitcnt vmcnt(8)" ::: "memory");
        else          asm volatile("s_waitcnt vmcnt(0)" ::: "memory");
        __builtin_amdgcn_sched_barrier(0);
#pragma unroll
        for (int q = 0; q < 8; ++q)
            *(ushort8*)(hb + swzH(sm, seg * 128 + q * 16)) = hv[q];
        asm volatile("s_waitcnt lgkmcnt(0)" ::: "memory");
        __builtin_amdgcn_s_barrier();          // raw: no auto vmcnt(0) drain
        __builtin_amdgcn_sched_barrier(0);

        // ---- D: h-side MFMA (kc 16..47) ----
#pragma unroll
        for (int kk = 4; kk < 12; ++kk) {
            short8 a0 = *(const short8*)(hb + swzH(lrow, (4 * kk - 16 + 0) * 64 + kg * 16));
            short8 a1 = *(const short8*)(hb + swzH(lrow, (4 * kk - 16 + 1) * 64 + kg * 16));
            short8 a2 = *(const short8*)(hb + swzH(lrow, (4 * kk - 16 + 2) * 64 + kg * 16));
            short8 a3 = *(const short8*)(hb + swzH(lrow, (4 * kk - 16 + 3) * 64 + kg * 16));
            acc0 = __builtin_amdgcn_mfma_f32_16x16x32_bf16(a0, Bf[4 * kk + 0], acc0, 0, 0, 0);
            acc1 = __builtin_amdgcn_mfma_f32_16x16x32_bf16(a1, Bf[4 * kk + 1], acc1, 0, 0, 0);
            acc2 = __builtin_amdgcn_mfma_f32_16x16x32_bf16(a2, Bf[4 * kk + 2], acc2, 0, 0, 0);
            acc3 = __builtin_amdgcn_mfma_f32_16x16x32_bf16(a3, Bf[4 * kk + 3], acc3, 0, 0, 0);
        }

        // ---- E: epilogue. C row = kg*4 + r, col = ncol (R0 layout: quarter-
        // wave lanes write 32B-contiguous runs; R6 proved C^T packing worse) ----
        if (!has_next) {
#pragma unroll
            for (int r = 0; r < 4; ++r) {
                float pre = acc0[r] + acc1[r] + acc2[r] + acc3[r] + bias;
                out[(size_t)(g * GROWS + kg * 4 + r) * HDIM + ncol] = fast_tanh(pre);
            }
            break;
        }
        {
            unsigned short* hdst = hbuf + (size_t)((t + 1) & 1) * HBUF_ELEMS;
#pragma unroll
            for (int r = 0; r < 4; ++r) {
                float pre = acc0[r] + acc1[r] + acc2[r] + acc3[r] + bias;
                float hvf = fast_tanh(pre);
                st_h16_c<FAST>(hdst + (size_t)(g * GROWS + kg * 4 + r) * HDIM + ncol, f2bf(hvf));
            }
        }

        // ---- F: drain stores (L2 ack in FAST) then per-wave publish.
        // Flag store plain in FAST: h-data is already committed to L2 by the
        // drain above, so write-through order L2-visibility is preserved; its
        // own ack is paid at the next poll's vmcnt(0) — now ~250cy not ~1100.
        asm volatile("s_waitcnt vmcnt(0)" ::: "memory");
        __builtin_amdgcn_sched_barrier(0);
        if (lane == 0) st_u32_c<FAST>(myflag, (unsigned int)(t + 1));

        // ---- G: stage x(t+1) regs -> xs[(t+1)&1] (no waits) ----
        {
            char* xnxt = xb + ((t + 1) & 1) * XBUFB;
#pragma unroll
            for (int q = 0; q < 4; ++q) {
                float4 a = xv[2 * q], b = xv[2 * q + 1];
                ushort8 w;
                w[0] = f2bf(a.x); w[1] = f2bf(a.y); w[2] = f2bf(a.z); w[3] = f2bf(a.w);
                w[4] = f2bf(b.x); w[5] = f2bf(b.y); w[6] = f2bf(b.z); w[7] = f2bf(b.w);
                *(ushort8*)(xnxt + swzX(sm, seg * 64 + q * 16)) = w;
            }
        }

        // ---- loop end: hs/xs reuse guard ----
        asm volatile("s_waitcnt lgkmcnt(0)" ::: "memory");
        __builtin_amdgcn_s_barrier();
        __builtin_amdgcn_sched_barrier(0);
    }
}

// ---------------------------------------------------------------------------
// Handshake (completed on HW, R8): exchange HW_REG_XCC_ID via the proven
// sc0 sc1 path; all 128 blocks co-resident (1 block/CU). Same-XCD group ->
// FAST (plain h + flag stores, L2-ack drains); else exact-R0 SLOW path.
__global__ __launch_bounds__(256, 1) void rnn_fused(
        const float* __restrict__ x, const unsigned short* __restrict__ WT,
        const float* __restrict__ bsum, unsigned short* __restrict__ hbuf,
        unsigned int* __restrict__ flags, float* __restrict__ out) {
    __shared__ unsigned short xs[2 * GROWS * IDIM];   // 32 KB (double-buffered x tile)
    __shared__ unsigned short hs[GROWS * HDIM];       // 32 KB (h tile)
    const int tid  = threadIdx.x;
    const int bid  = blockIdx.x;
    const int g    = bid & 7;
    const int lane = tid & 63;

    unsigned int myxcd;
    asm volatile("s_getreg_b32 %0, hwreg(HW_REG_XCC_ID)" : "=s"(myxcd));
    unsigned int* const xcdmap = flags + NFLAG;          // [NBLK]
    unsigned int* const hsflag = flags + NFLAG + NBLK;   // [NBLK]
    if (tid == 0) {
        st_u32_if(&xcdmap[bid], myxcd + 1u);
        asm volatile("s_waitcnt vmcnt(0)" ::: "memory");
        st_u32_if(&hsflag[bid], 1u);
    }
    // peers of group g are bids g, g+8, ..., g+120; lanes 16..63 duplicate
    const int peer = g + 8 * (lane & 15);
    while (true) {
        unsigned int v = ld_u32_if(&hsflag[peer]);
        if (__all(v != 0)) break;
    }
    const unsigned int px = ld_u32_if(&xcdmap[peer]);
    // verdict symmetric across the group (same 16 values) -> same path chosen
    if (__all(px == myxcd + 1u))
        rnn_loop<true >(x, WT, bsum, hbuf, flags, out, xs, hs, tid, bid);
    else
        rnn_loop<false>(x, WT, bsum, hbuf, flags, out, xs, hs, tid, bid);
}

// ---------------------------------------------------------------------------
extern "C" void kernel_launch(void* const* d_in, const int* in_sizes, int n_in,
                              void* d_out, int out_size, void* d_ws, size_t ws_size,
                              hipStream_t stream) {
    const float* x  = (const float*)d_in[0];
    const float* h0 = (const float*)d_in[1];
    const float* Wx = (const float*)d_in[2];
    const float* bx = (const float*)d_in[3];
    const float* Wh = (const float*)d_in[4];
    const float* bh = (const float*)d_in[5];
    float* out = (float*)d_out;

    // workspace layout (128B-aligned pieces)
    const size_t OFF_WT = 0;                    // 1024*1536 bf16 = 3,145,728 B
    const size_t OFF_BS = 3145728;              // 1024 f32 = 4096 B
    const size_t OFF_HB = 3149824;              // 2*128*1024 bf16 = 524,288 B
    const size_t OFF_FL = 3674112;              // (512 + 256) u32 = 3072 B
    const size_t WS_NEED = 3677184;
    if (ws_size < WS_NEED) {                    // diagnostic: absmax ~1e6 => ws too small
        hipLaunchKernelGGL(ws_fail_kernel, dim3(1), dim3(1), 0, stream, out);
        return;
    }

    unsigned short* WT    = (unsigned short*)((char*)d_ws + OFF_WT);
    float*          bsum  = (float*)((char*)d_ws + OFF_BS);
    unsigned short* hbuf  = (unsigned short*)((char*)d_ws + OFF_HB);
    unsigned int*   flags = (unsigned int*)((char*)d_ws + OFF_FL);

    prep_transpose<<<dim3(IDIM / 32, HDIM / 32), dim3(32, 8), 0, stream>>>(Wx, WT, 0);
    prep_transpose<<<dim3(HDIM / 32, HDIM / 32), dim3(32, 8), 0, stream>>>(Wh, WT, IDIM);
    const int misc_total = HBUF_ELEMS + HDIM + NFLAG + 2 * NBLK;
    prep_misc<<<dim3((misc_total + 255) / 256), dim3(256), 0, stream>>>(
        h0, bx, bh, bsum, hbuf, flags);
    rnn_fused<<<dim3(NBLK), dim3(256), 0, stream>>>(
        x, WT, bsum, hbuf, flags, out);
}